// Round 4
// baseline (538.319 us; speedup 1.0000x reference)
//
#include <hip/hip_runtime.h>
#include <math.h>

// out[i, j, k] = K[j, k] * a[i, k],  K[j, m] = exp(-GAMMA * ||a_j - b_m||^2)
// N = 1024, M = D = 128. rotation/entangle params dead (softmax over len-1 axis).
// Output = 512 MiB fp32 -> pure write-BW problem.
//
// Round-3 showed linear fill-shaped stores are the key (539 -> 455 us).
// Remaining delta vs the 6.33 TB/s fill: one L2 load interleaved with every
// store. This version hoists ALL operands to registers: block (g, s) owns
// i-group g (8 rows) x j-slab s (128 rows). Per thread: 16 kv + 8 av float4
// loads up front, then 128 iterations of {4 v_mul + global_store_dwordx4}
// with register-only operands -- structurally identical to the fill.
// K L2 read traffic drops 8x (512 MB -> 64 MB). Each block writes 8
// contiguous 64 KB streams.

#define GAMMA_F 1.0f
#define N_ROWS  1024
#define DIM     128

typedef float floatx4 __attribute__((ext_vector_type(4)));

// ---------------------------------------------------------------------------
// Kernel 1: K[j, m] = exp(-||a_j - b_m||^2).  grid = 1024 blocks, 128 threads.
// (verified kernel, bit-identical arithmetic since round 0)
// ---------------------------------------------------------------------------
__global__ __launch_bounds__(DIM) void compute_K_kernel(
    const float* __restrict__ a,
    const float* __restrict__ b,
    float* __restrict__ K)
{
    __shared__ float4 a_sh[DIM / 4];
    const int j = blockIdx.x;
    const int m = threadIdx.x;

    if (m < DIM / 4) {
        a_sh[m] = reinterpret_cast<const float4*>(a + (size_t)j * DIM)[m];
    }
    __syncthreads();

    const float4* b4 = reinterpret_cast<const float4*>(b + (size_t)m * DIM);
    float acc = 0.0f;
#pragma unroll 8
    for (int d = 0; d < DIM / 4; ++d) {
        const float4 av = a_sh[d];
        const float4 bv = b4[d];
        const float dx = av.x - bv.x;
        const float dy = av.y - bv.y;
        const float dz = av.z - bv.z;
        const float dw = av.w - bv.w;
        acc = fmaf(dx, dx, acc);
        acc = fmaf(dy, dy, acc);
        acc = fmaf(dz, dz, acc);
        acc = fmaf(dw, dw, acc);
    }
    K[(size_t)j * DIM + m] = expf(-GAMMA_F * acc);
}

// ---------------------------------------------------------------------------
// Kernel 2: register-resident streaming multiply.
//   bid in [0, 1024): g = bid >> 3 (i-group: i = g*8 + r), s = bid & 7 (j-slab)
//   kv[it] = K4[(s*128 + (tid>>5) + it*8) * 32 + k4]   (16 loads, hoisted)
//   av[r]  = a4[(g*8 + r) * 32 + k4]                   (8 loads, hoisted)
//   out4 idx = i*32768 + s*4096 + tid + it*256         (fully linear per span)
// Inner loop: 128 stores, register-only operands. All array indices are
// compile-time constants after unrolling -> registers, no scratch.
// ---------------------------------------------------------------------------
__global__ __launch_bounds__(256) void stream_mul_kernel(
    const floatx4* __restrict__ a4,
    const floatx4* __restrict__ K4,
    floatx4* __restrict__ out4)
{
    const unsigned tid = threadIdx.x;
    const unsigned bid = blockIdx.x;
    const unsigned g   = bid >> 3;        // 0..127  (i-group)
    const unsigned s   = bid & 7u;        // 0..7    (j-slab)
    const unsigned k4  = tid & 31u;
    const unsigned jr  = tid >> 5;        // 0..7    (j-row within 8-row group)

    floatx4 kv[16];
#pragma unroll
    for (int it = 0; it < 16; ++it) {
        kv[it] = K4[(s * 128u + jr + (unsigned)it * 8u) * 32u + k4];
    }

    floatx4 av[8];
#pragma unroll
    for (int r = 0; r < 8; ++r) {
        av[r] = a4[(g * 8u + r) * 32u + k4];
    }

    const size_t base = (size_t)g * 8u * 32768u + (size_t)s * 4096u + tid;

#pragma unroll
    for (int r = 0; r < 8; ++r) {
        floatx4* __restrict__ o = out4 + base + (size_t)r * 32768u;
#pragma unroll
        for (int it = 0; it < 16; ++it) {
            o[(size_t)it * 256u] = av[r] * kv[it];
        }
    }
}

extern "C" void kernel_launch(void* const* d_in, const int* in_sizes, int n_in,
                              void* d_out, int out_size, void* d_ws, size_t ws_size,
                              hipStream_t stream)
{
    const float* a = reinterpret_cast<const float*>(d_in[0]);   // [1024, 128]
    const float* b = reinterpret_cast<const float*>(d_in[1]);   // [128, 128]
    // d_in[2], d_in[3] (rotation/entangle params) are mathematically dead.

    float* K = reinterpret_cast<float*>(d_ws);                  // [1024,128] scratch

    compute_K_kernel<<<N_ROWS, DIM, 0, stream>>>(a, b, K);

    stream_mul_kernel<<<1024, 256, 0, stream>>>(
        reinterpret_cast<const floatx4*>(a),
        reinterpret_cast<const floatx4*>(K),
        reinterpret_cast<floatx4*>(d_out));
}

// Round 5
// 458.736 us; speedup vs baseline: 1.1735x; 1.1735x over previous
//
#include <hip/hip_runtime.h>
#include <math.h>

// out[i, j, k] = K[j, k] * a[i, k],  K[j, m] = exp(-GAMMA * ||a_j - b_m||^2)
// N = 1024, M = D = 128. rotation/entangle params dead (softmax over len-1 axis).
// Output = 512 MiB fp32 -> pure write-BW problem.
//
// ROUND-3 STRUCTURE (verified 455 us) + ONE change: nontemporal stores.
// Lesson from rounds 3/4: device-wide LINEAR write front is the dominant
// variable (each block = one contiguous 64 KB span, consecutive blocks ->
// consecutive spans). Round 4 proved the L2-read interleave is NOT the
// limiter. Remaining hypothesis: store stream write-allocating in L2;
// NT stores bypass L2, freeing TCC for the K reads.

#define GAMMA_F 1.0f
#define N_ROWS  1024
#define DIM     128

typedef float floatx4 __attribute__((ext_vector_type(4)));

// ---------------------------------------------------------------------------
// Kernel 1: K[j, m] = exp(-||a_j - b_m||^2).  grid = 1024 blocks, 128 threads.
// (verified kernel, bit-identical arithmetic since round 0)
// ---------------------------------------------------------------------------
__global__ __launch_bounds__(DIM) void compute_K_kernel(
    const float* __restrict__ a,
    const float* __restrict__ b,
    float* __restrict__ K)
{
    __shared__ float4 a_sh[DIM / 4];
    const int j = blockIdx.x;
    const int m = threadIdx.x;

    if (m < DIM / 4) {
        a_sh[m] = reinterpret_cast<const float4*>(a + (size_t)j * DIM)[m];
    }
    __syncthreads();

    const float4* b4 = reinterpret_cast<const float4*>(b + (size_t)m * DIM);
    float acc = 0.0f;
#pragma unroll 8
    for (int d = 0; d < DIM / 4; ++d) {
        const float4 av = a_sh[d];
        const float4 bv = b4[d];
        const float dx = av.x - bv.x;
        const float dy = av.y - bv.y;
        const float dz = av.z - bv.z;
        const float dw = av.w - bv.w;
        acc = fmaf(dx, dx, acc);
        acc = fmaf(dy, dy, acc);
        acc = fmaf(dz, dz, acc);
        acc = fmaf(dw, dw, acc);
    }
    K[(size_t)j * DIM + m] = expf(-GAMMA_F * acc);
}

// ---------------------------------------------------------------------------
// Kernel 2: linear streaming multiply, fill-shaped (round-3 verified mapping).
//   flat float4 index v = bid*4096 + tid + it*256, it = 0..15
//   k4 = tid & 31; i = bid >> 3 (constant per block)
//   j  = (bid&7)*128 + (tid>>5) + it*8
// Each block writes contiguous [bid*64KB, (bid+1)*64KB). 8192 blocks.
// ONLY change vs round 3: __builtin_nontemporal_store.
// ---------------------------------------------------------------------------
__global__ __launch_bounds__(256) void stream_mul_kernel(
    const floatx4* __restrict__ a4,
    const floatx4* __restrict__ K4,
    floatx4* __restrict__ out4)
{
    const unsigned tid  = threadIdx.x;
    const unsigned bid  = blockIdx.x;
    const unsigned base = bid * 4096u;            // float4 units, 64 KB/block

    const unsigned k4 = tid & 31u;
    const unsigned i  = bid >> 3;                 // 8 blocks per i-slab (512 KB)
    const floatx4 av  = a4[i * 32u + k4];         // loop-invariant

    const unsigned j0 = (bid & 7u) * 128u + (tid >> 5);
    const unsigned v0 = base + tid;

#pragma unroll
    for (int it = 0; it < 16; ++it) {
        const floatx4 kv = K4[(j0 + (unsigned)it * 8u) * 32u + k4];
        __builtin_nontemporal_store(av * kv, &out4[v0 + (unsigned)it * 256u]);
    }
}

extern "C" void kernel_launch(void* const* d_in, const int* in_sizes, int n_in,
                              void* d_out, int out_size, void* d_ws, size_t ws_size,
                              hipStream_t stream)
{
    const float* a = reinterpret_cast<const float*>(d_in[0]);   // [1024, 128]
    const float* b = reinterpret_cast<const float*>(d_in[1]);   // [128, 128]
    // d_in[2], d_in[3] (rotation/entangle params) are mathematically dead.

    float* K = reinterpret_cast<float*>(d_ws);                  // [1024,128] scratch

    compute_K_kernel<<<N_ROWS, DIM, 0, stream>>>(a, b, K);

    const unsigned n_vec4  = (unsigned)(out_size / 16);         // 33,554,432 float4
    const unsigned nblocks = n_vec4 / 4096u;                    // 8192
    stream_mul_kernel<<<nblocks, 256, 0, stream>>>(
        reinterpret_cast<const floatx4*>(a),
        reinterpret_cast<const floatx4*>(K),
        reinterpret_cast<floatx4*>(d_out));
}